// Round 13
// baseline (113.863 us; speedup 1.0000x reference)
//
#include <hip/hip_runtime.h>

#define NH        32
#define HID       128
#define E_TOT     262144
#define CH_ELEM   16384     // main chunk: 16 sl * 1024 elems = 32 KB
#define NCH_MAIN  8         // 8 * 16 = 128 s-steps
#define TAIL_OFF  131072    // 8 * 16384
#define TAIL_ELEM 8192      // tail chunk: 8 sl (sl 0..4 valid, 5..7 zero)

typedef float        f32x4 __attribute__((ext_vector_type(4)));
typedef short        s16x8 __attribute__((ext_vector_type(8)));
typedef unsigned int u32x4 __attribute__((ext_vector_type(4)));

static __device__ __forceinline__ short f2bf(float f) {
    __bf16 b = (__bf16)f;
    return __builtin_bit_cast(short, b);
}
static __device__ __forceinline__ float selu_f(float x) {
    const float kScale  = 1.0507009873554804934193349852946f;
    const float kAlphaS = 1.7580993408473768599402175208123f; // scale*alpha
    float neg = kAlphaS * (__expf(x) - 1.0f);
    return x > 0.0f ? kScale * x : neg;
}

// ---- pre-kernel: build WT in chunk-linear, LANE-LINEAR LDS order.
// main region gid < 131072: bits [c:3][sl:4][ih:1][g:2][lrow:4][p:3]
//   kappa = c*512 + sl*32 + g*8 + p   (0..4095)  -> W_A2[kappa>>5][i*32 + (kappa&31)]
// tail region r = gid-131072 < 8192: bits [sl:3][ih:1][g:2][lrow:4][p:3]
//   kappa = 4096 + sl*32 + g*8 + p:
//     4096..4127 -> b_A2[i*32 + (kappa-4096)]
//     4128..4255 -> W_b2[kappa-4128][i]
//     else 0
// i = ih*16 + lrow in both regions.
__global__ void wt_build(const float* __restrict__ W_A2, const float* __restrict__ b_A2,
                         const float* __restrict__ W_b2, unsigned short* __restrict__ WT) {
    int gid = blockIdx.x * 256 + threadIdx.x;
    if (gid >= TAIL_OFF + TAIL_ELEM) return;
    int ih, g, lrow, p, kap;
    if (gid < TAIL_OFF) {
        int c  = gid >> 14;
        int r  = gid & 16383;
        int sl = r >> 10;
        ih   = (r >> 9) & 1;
        g    = (r >> 7) & 3;
        lrow = (r >> 3) & 15;
        p    = r & 7;
        kap  = c * 512 + sl * 32 + g * 8 + p;
    } else {
        int r  = gid - TAIL_OFF;
        int sl = r >> 10;
        ih   = (r >> 9) & 1;
        g    = (r >> 7) & 3;
        lrow = (r >> 3) & 15;
        p    = r & 7;
        kap  = 4096 + sl * 32 + g * 8 + p;
    }
    int i = ih * 16 + lrow;
    float v = 0.0f;
    if (kap < 4096)      v = W_A2[(kap >> 5) * 1024 + i * 32 + (kap & 31)];
    else if (kap < 4128) v = b_A2[i * 32 + (kap - 4096)];
    else if (kap < 4256) v = W_b2[(kap - 4128) * 32 + i];
    WT[gid] = (unsigned short)f2bf(v);
}

typedef const __attribute__((address_space(1))) unsigned int GU32;
typedef __attribute__((address_space(3))) unsigned int LU32;
static __device__ __forceinline__ void gload_lds16(const void* g, void* l) {
    __builtin_amdgcn_global_load_lds((GU32*)g, (LU32*)l, 16, 0, 0);
}

// i-split waves: 512 threads = 8 waves; wave wid: eg = wid>>1 (64-edge group),
// ih = wid&1 (i-half). Each wave computes D[i in ih-half (16 rows), 64 edges].
//   A = W'T ih-half slice from LDS: lane l reads bytes (sl*2048 + ih*1024 + l*16)
//   B = h fragment in regs (bf16 once): col-edge = ct*16+lrow, k = g*8+p
//   per sl: 1 ds_read_b128, 4 MFMAs into t[], then fma accumulate with u
//   u: bf16-pair packed per 2 sl, one __shfl per ct per 2 sl (in-wave owners)
__global__ void __launch_bounds__(512, 4)
msg_main(const float* __restrict__ h_i, const float* __restrict__ e_ij,
         const float* __restrict__ W_A1, const float* __restrict__ b_A1,
         const float* __restrict__ W_b1, const float* __restrict__ b_b1,
         const float* __restrict__ b_b2,
         const unsigned short* __restrict__ WT,
         float* __restrict__ out)
{
    __shared__ unsigned short ldsW[CH_ELEM];      // 32 KB, single buffer
    __shared__ float cA1[HID], cBA1[HID], cB1a[HID], cB1b[HID], cb2[NH];

    const int tid  = threadIdx.x;
    const int lane = tid & 63;
    const int wid  = tid >> 6;      // 0..7
    const int ih   = wid & 1;       // i-half of this wave
    const int eg   = wid >> 1;      // edge-group 0..3
    const int lrow = lane & 15;
    const int g    = lane >> 4;
    const int e0   = blockIdx.x * 256 + eg * 64;

    if (tid < HID) {
        cA1[tid]  = W_A1[tid];
        cBA1[tid] = b_A1[tid];
        cB1a[tid] = W_b1[tid];
        cB1b[tid] = b_b1[tid];
    }
    if (tid < NH) cb2[tid] = b_b2[tid];

    // lane owns edge e0+lane (within its wave)
    const float ev_own = e_ij[e0 + lane];

    // persistent bf16 h fragments (B operand)
    s16x8 hb[4];
    #pragma unroll
    for (int ct = 0; ct < 4; ++ct) {
        int er = e0 + ct * 16 + lrow;
        const float* hp = h_i + er * 32 + g * 8;
        f32x4 h0 = *(const f32x4*)hp;
        f32x4 h1 = *(const f32x4*)(hp + 4);
        #pragma unroll
        for (int p = 0; p < 4; ++p) {
            hb[ct][p]     = f2bf(h0[p]);
            hb[ct][p + 4] = f2bf(h1[p]);
        }
    }

    // per-col-tile edge scalar (for tail B construction)
    float ev_ct[4];
    #pragma unroll
    for (int ct = 0; ct < 4; ++ct) ev_ct[ct] = __shfl(ev_own, ct * 16 + lrow);

    f32x4 acc[4];
    #pragma unroll
    for (int ct = 0; ct < 4; ++ct) acc[ct] = (f32x4){0.f, 0.f, 0.f, 0.f};
    const f32x4 zf = (f32x4){0.f, 0.f, 0.f, 0.f};

    unsigned int u_pk[8];   // bf16 pair per 2 s-steps

    __syncthreads();        // consts visible

    for (int c = 0; c < NCH_MAIN; ++c) {
        // stage chunk c (32 KB): linear copy, 4 x 16B per thread (512 threads)
        #pragma unroll
        for (int r = 0; r < 4; ++r) {
            int eo = r * 4096 + tid * 8;
            gload_lds16(WT + c * CH_ELEM + eo, &ldsW[eo]);
        }
        // u for 16 s-steps of this chunk, packed bf16x2 per sl-pair
        #pragma unroll
        for (int sp = 0; sp < 8; ++sp) {
            int s = c * 16 + sp * 2;
            float u0 = selu_f(fmaf(ev_own, cA1[s],     cBA1[s]));
            float u1 = selu_f(fmaf(ev_own, cA1[s + 1], cBA1[s + 1]));
            u_pk[sp] = ((unsigned int)(unsigned short)f2bf(u0))
                     | (((unsigned int)(unsigned short)f2bf(u1)) << 16);
        }
        __syncthreads();    // staging arrived (barrier drains vmcnt)

        #pragma unroll
        for (int sp = 0; sp < 8; ++sp) {
            // one shuffle per ct covers both sl of this pair
            unsigned int upc[4];
            #pragma unroll
            for (int ct = 0; ct < 4; ++ct)
                upc[ct] = __shfl(u_pk[sp], ct * 16 + lrow);

            #pragma unroll
            for (int half = 0; half < 2; ++half) {
                const int sl = sp * 2 + half;
                u32x4 ra = *(const u32x4*)&ldsW[sl * 1024 + ih * 512 + lane * 8];
                s16x8 A  = __builtin_bit_cast(s16x8, ra);
                f32x4 u4[4];
                #pragma unroll
                for (int ct = 0; ct < 4; ++ct) {
                    unsigned int w = half == 0 ? (upc[ct] << 16) : (upc[ct] & 0xffff0000u);
                    float uf = __builtin_bit_cast(float, w);
                    u4[ct] = (f32x4){uf, uf, uf, uf};
                }
                f32x4 t[4];
                #pragma unroll
                for (int ct = 0; ct < 4; ++ct)
                    t[ct] = __builtin_amdgcn_mfma_f32_16x16x32_bf16(A, hb[ct], zf, 0, 0, 0);
                #pragma unroll
                for (int ct = 0; ct < 4; ++ct)
                    acc[ct] = __builtin_elementwise_fma(t[ct], u4[ct], acc[ct]);
            }
        }
        __syncthreads();    // all reads done before next chunk overwrites
    }

    // ---- tail chunk: stage sl 0..5 (need sl 0..4 = 5120 elems; 2 rounds x 512thr = 8192)
    #pragma unroll
    for (int r = 0; r < 2; ++r) {
        int eo = r * 4096 + tid * 8;
        gload_lds16(WT + TAIL_OFF + eo, &ldsW[eo]);
    }
    __syncthreads();

    // sl 0: b_A2 (pseudo-u = 1, B = h)
    {
        u32x4 ra = *(const u32x4*)&ldsW[ih * 512 + lane * 8];
        s16x8 A  = __builtin_bit_cast(s16x8, ra);
        #pragma unroll
        for (int ct = 0; ct < 4; ++ct)
            acc[ct] = __builtin_amdgcn_mfma_f32_16x16x32_bf16(A, hb[ct], acc[ct], 0, 0, 0);
    }
    // sl 1..4: b-path (A = W_b2 cols of this ih-half, B = selu(e*W_b1 + b_b1))
    #pragma unroll
    for (int q = 0; q < 4; ++q) {
        u32x4 ra = *(const u32x4*)&ldsW[(q + 1) * 1024 + ih * 512 + lane * 8];
        s16x8 A  = __builtin_bit_cast(s16x8, ra);
        int tb = q * 32 + g * 8;
        f32x4 wb0 = *(const f32x4*)&cB1a[tb];
        f32x4 wb1 = *(const f32x4*)&cB1a[tb + 4];
        f32x4 bb0 = *(const f32x4*)&cB1b[tb];
        f32x4 bb1 = *(const f32x4*)&cB1b[tb + 4];
        #pragma unroll
        for (int ct = 0; ct < 4; ++ct) {
            s16x8 B;
            #pragma unroll
            for (int p = 0; p < 4; ++p) {
                B[p]     = f2bf(selu_f(fmaf(ev_ct[ct], wb0[p], bb0[p])));
                B[p + 4] = f2bf(selu_f(fmaf(ev_ct[ct], wb1[p], bb1[p])));
            }
            acc[ct] = __builtin_amdgcn_mfma_f32_16x16x32_bf16(A, B, acc[ct], 0, 0, 0);
        }
    }

    // ---- epilogue: add b_b2, store. C/D: col(lane&15)=e_local, row(g*4+r)=i_local
    {
        f32x4 b2v = *(const f32x4*)&cb2[ih * 16 + g * 4];
        #pragma unroll
        for (int ct = 0; ct < 4; ++ct) {
            int edge = e0 + ct * 16 + lrow;
            f32x4 vo = acc[ct] + b2v;
            *(f32x4*)&out[edge * 32 + ih * 16 + g * 4] = vo;
        }
    }
}

extern "C" void kernel_launch(void* const* d_in, const int* in_sizes, int n_in,
                              void* d_out, int out_size, void* d_ws, size_t ws_size,
                              hipStream_t stream) {
    const float* h_i  = (const float*)d_in[0];
    const float* e_ij = (const float*)d_in[1];
    const float* W_A1 = (const float*)d_in[2];
    const float* b_A1 = (const float*)d_in[3];
    const float* W_A2 = (const float*)d_in[4];
    const float* b_A2 = (const float*)d_in[5];
    const float* W_b1 = (const float*)d_in[6];
    const float* b_b1 = (const float*)d_in[7];
    const float* W_b2 = (const float*)d_in[8];
    const float* b_b2 = (const float*)d_in[9];

    unsigned short* WT = (unsigned short*)d_ws;   // (131072 + 8192) * 2 = 278,528 B

    wt_build<<<(TAIL_OFF + TAIL_ELEM + 255) / 256, 256, 0, stream>>>(W_A2, b_A2, W_b2, WT);
    msg_main<<<E_TOT / 256, 512, 0, stream>>>(h_i, e_ij, W_A1, b_A1, W_b1, b_b1,
                                              b_b2, WT, (float*)d_out);
}

// Round 15
// 97.302 us; speedup vs baseline: 1.1702x; 1.1702x over previous
//
#include <hip/hip_runtime.h>

#define NH        32
#define HID       128
#define E_TOT     262144
#define CH_ELEM   8192      // chunk: 8 sl * 1024 elems = 16 KB
#define NCH_MAIN  16        // 16 * 8 = 128 s-steps
#define TAIL_OFF  131072    // 16 * 8192
#define TAIL_ELEM 8192      // tail chunk: 8 sl (sl 0..4 valid, 5..7 zero)

typedef float        f32x4 __attribute__((ext_vector_type(4)));
typedef short        s16x8 __attribute__((ext_vector_type(8)));
typedef unsigned int u32x4 __attribute__((ext_vector_type(4)));

static __device__ __forceinline__ short f2bf(float f) {
    __bf16 b = (__bf16)f;
    return __builtin_bit_cast(short, b);
}
static __device__ __forceinline__ float selu_f(float x) {
    const float kScale  = 1.0507009873554804934193349852946f;
    const float kAlphaS = 1.7580993408473768599402175208123f; // scale*alpha
    float neg = kAlphaS * (__expf(x) - 1.0f);
    return x > 0.0f ? kScale * x : neg;
}

// ---- pre-kernel: build WT in chunk-linear, LANE-LINEAR LDS order.
// (VERBATIM from passing R8 — kappa = 32*(gid>>10) + f(gid&511) is invariant
// to the 16sl-vs-8sl chunk split, so the same WT serves 8-sl chunks.)
// main region gid < 131072: bits [c:3][sl:4][it:1][g:2][lrow:4][p:3]
//   kappa = c*512 + sl*32 + g*8 + p   (0..4095)  -> W_A2[kappa>>5][i*32 + (kappa&31)]
// tail region r = gid-131072 < 8192: bits [sl:3][it:1][g:2][lrow:4][p:3]
//   kappa = 4096 + sl*32 + g*8 + p:
//     4096..4127 -> b_A2[i*32 + (kappa-4096)]
//     4128..4255 -> W_b2[kappa-4128][i]
//     else 0
// i = it*16 + lrow in both regions.
__global__ void wt_build(const float* __restrict__ W_A2, const float* __restrict__ b_A2,
                         const float* __restrict__ W_b2, unsigned short* __restrict__ WT) {
    int gid = blockIdx.x * 256 + threadIdx.x;
    if (gid >= TAIL_OFF + TAIL_ELEM) return;
    int it, g, lrow, p, kap;
    if (gid < TAIL_OFF) {
        int c  = gid >> 14;
        int r  = gid & 16383;
        int sl = r >> 10;
        it   = (r >> 9) & 1;
        g    = (r >> 7) & 3;
        lrow = (r >> 3) & 15;
        p    = r & 7;
        kap  = c * 512 + sl * 32 + g * 8 + p;
    } else {
        int r  = gid - TAIL_OFF;
        int sl = r >> 10;
        it   = (r >> 9) & 1;
        g    = (r >> 7) & 3;
        lrow = (r >> 3) & 15;
        p    = r & 7;
        kap  = 4096 + sl * 32 + g * 8 + p;
    }
    int i = it * 16 + lrow;
    float v = 0.0f;
    if (kap < 4096)      v = W_A2[(kap >> 5) * 1024 + i * 32 + (kap & 31)];
    else if (kap < 4128) v = b_A2[i * 32 + (kap - 4096)];
    else if (kap < 4256) v = W_b2[(kap - 4128) * 32 + i];
    WT[gid] = (unsigned short)f2bf(v);
}

typedef const __attribute__((address_space(1))) unsigned int GU32;
typedef __attribute__((address_space(3))) unsigned int LU32;
static __device__ __forceinline__ void gload_lds16(const void* g, void* l) {
    __builtin_amdgcn_global_load_lds((GU32*)g, (LU32*)l, 16, 0, 0);
}

// Orientation: D[i_local(row), e_local(col)] per (ct, it) tile.
//   wave = 64 edges (e0 = blk*256 + wid*64)
//   A = W'T slice from LDS: lane l reads bytes (sl*2048 + it*1024 + l*16) -> conflict-free
//   B = h fragment in regs (bf16 once): col-edge = ct*16+lrow, k = g*8+p
//   per sl: 4 MFMAs per it-tile into t[], then vector-fma accumulate with u
//   u via in-wave __shfl of register-held u_own
// 8-sl chunks -> LDS 18.6 KB -> 8 blocks/CU (32 waves) at VGPR<=64.
__global__ void __launch_bounds__(256, 4)
msg_main(const float* __restrict__ h_i, const float* __restrict__ e_ij,
         const float* __restrict__ W_A1, const float* __restrict__ b_A1,
         const float* __restrict__ W_b1, const float* __restrict__ b_b1,
         const float* __restrict__ b_b2,
         const unsigned short* __restrict__ WT,
         float* __restrict__ out)
{
    __shared__ unsigned short ldsW[CH_ELEM];      // 16 KB, single buffer
    __shared__ float cA1[HID], cBA1[HID], cB1a[HID], cB1b[HID], cb2[NH];

    const int tid  = threadIdx.x;
    const int lane = tid & 63;
    const int wid  = tid >> 6;
    const int lrow = lane & 15;
    const int g    = lane >> 4;
    const int e0   = blockIdx.x * 256 + wid * 64;

    if (tid < HID) {
        cA1[tid]  = W_A1[tid];
        cBA1[tid] = b_A1[tid];
        cB1a[tid] = W_b1[tid];
        cB1b[tid] = b_b1[tid];
    }
    if (tid < NH) cb2[tid] = b_b2[tid];

    // lane owns edge e0+lane
    const float ev_own = e_ij[e0 + lane];

    // persistent bf16 h fragments (B operand)
    s16x8 hb[4];
    #pragma unroll
    for (int ct = 0; ct < 4; ++ct) {
        int er = e0 + ct * 16 + lrow;
        const float* hp = h_i + er * 32 + g * 8;
        f32x4 h0 = *(const f32x4*)hp;
        f32x4 h1 = *(const f32x4*)(hp + 4);
        #pragma unroll
        for (int p = 0; p < 4; ++p) {
            hb[ct][p]     = f2bf(h0[p]);
            hb[ct][p + 4] = f2bf(h1[p]);
        }
    }

    // per-col-tile edge scalar (for tail B construction)
    float ev_ct[4];
    #pragma unroll
    for (int ct = 0; ct < 4; ++ct) ev_ct[ct] = __shfl(ev_own, ct * 16 + lrow);

    f32x4 acc[4][2];
    #pragma unroll
    for (int ct = 0; ct < 4; ++ct)
        #pragma unroll
        for (int it = 0; it < 2; ++it)
            acc[ct][it] = (f32x4){0.f, 0.f, 0.f, 0.f};
    const f32x4 zf = (f32x4){0.f, 0.f, 0.f, 0.f};

    float u_own[8];

    __syncthreads();        // consts visible

    for (int c = 0; c < NCH_MAIN; ++c) {
        // stage chunk c (16 KB): linear copy, 4 x 16B per thread
        #pragma unroll
        for (int r = 0; r < 4; ++r) {
            int eo = r * 2048 + tid * 8;
            gload_lds16(WT + c * CH_ELEM + eo, &ldsW[eo]);
        }
        // u for the 8 s-steps of this chunk
        #pragma unroll
        for (int sl = 0; sl < 8; ++sl) {
            int s = c * 8 + sl;
            u_own[sl] = selu_f(fmaf(ev_own, cA1[s], cBA1[s]));
        }
        __syncthreads();    // staging arrived (barrier drains vmcnt)

        #pragma unroll
        for (int sl = 0; sl < 8; ++sl) {
            u32x4 r0 = *(const u32x4*)&ldsW[sl * 1024 +       lane * 8];
            u32x4 r1 = *(const u32x4*)&ldsW[sl * 1024 + 512 + lane * 8];
            s16x8 A0 = __builtin_bit_cast(s16x8, r0);
            s16x8 A1 = __builtin_bit_cast(s16x8, r1);
            f32x4 u4[4];
            #pragma unroll
            for (int ct = 0; ct < 4; ++ct) {
                float uv = __shfl(u_own[sl], ct * 16 + lrow);
                u4[ct] = (f32x4){uv, uv, uv, uv};
            }
            // it = 0: 4 MFMAs, then 4 vector fmas
            {
                f32x4 t[4];
                #pragma unroll
                for (int ct = 0; ct < 4; ++ct)
                    t[ct] = __builtin_amdgcn_mfma_f32_16x16x32_bf16(A0, hb[ct], zf, 0, 0, 0);
                #pragma unroll
                for (int ct = 0; ct < 4; ++ct)
                    acc[ct][0] = __builtin_elementwise_fma(t[ct], u4[ct], acc[ct][0]);
            }
            // it = 1
            {
                f32x4 t[4];
                #pragma unroll
                for (int ct = 0; ct < 4; ++ct)
                    t[ct] = __builtin_amdgcn_mfma_f32_16x16x32_bf16(A1, hb[ct], zf, 0, 0, 0);
                #pragma unroll
                for (int ct = 0; ct < 4; ++ct)
                    acc[ct][1] = __builtin_elementwise_fma(t[ct], u4[ct], acc[ct][1]);
            }
        }
        __syncthreads();    // all reads done before next chunk overwrites
    }

    // ---- tail chunk: stage sl 0..5 (need sl 0..4 = 5120 elems; 3 rounds = 6144)
    #pragma unroll
    for (int r = 0; r < 3; ++r) {
        int eo = r * 2048 + tid * 8;
        gload_lds16(WT + TAIL_OFF + eo, &ldsW[eo]);
    }
    __syncthreads();

    // sl 0: b_A2 (pseudo-u = 1, B = h)
    {
        u32x4 r0 = *(const u32x4*)&ldsW[      lane * 8];
        u32x4 r1 = *(const u32x4*)&ldsW[512 + lane * 8];
        s16x8 A0 = __builtin_bit_cast(s16x8, r0);
        s16x8 A1 = __builtin_bit_cast(s16x8, r1);
        #pragma unroll
        for (int ct = 0; ct < 4; ++ct) {
            acc[ct][0] = __builtin_amdgcn_mfma_f32_16x16x32_bf16(A0, hb[ct], acc[ct][0], 0, 0, 0);
            acc[ct][1] = __builtin_amdgcn_mfma_f32_16x16x32_bf16(A1, hb[ct], acc[ct][1], 0, 0, 0);
        }
    }
    // sl 1..4: b-path (A = W_b2 cols, B = selu(e*W_b1 + b_b1))
    #pragma unroll
    for (int q = 0; q < 4; ++q) {
        u32x4 r0 = *(const u32x4*)&ldsW[(q + 1) * 1024 +       lane * 8];
        u32x4 r1 = *(const u32x4*)&ldsW[(q + 1) * 1024 + 512 + lane * 8];
        s16x8 A0 = __builtin_bit_cast(s16x8, r0);
        s16x8 A1 = __builtin_bit_cast(s16x8, r1);
        int tb = q * 32 + g * 8;
        f32x4 wb0 = *(const f32x4*)&cB1a[tb];
        f32x4 wb1 = *(const f32x4*)&cB1a[tb + 4];
        f32x4 bb0 = *(const f32x4*)&cB1b[tb];
        f32x4 bb1 = *(const f32x4*)&cB1b[tb + 4];
        #pragma unroll
        for (int ct = 0; ct < 4; ++ct) {
            s16x8 B;
            #pragma unroll
            for (int p = 0; p < 4; ++p) {
                B[p]     = f2bf(selu_f(fmaf(ev_ct[ct], wb0[p], bb0[p])));
                B[p + 4] = f2bf(selu_f(fmaf(ev_ct[ct], wb1[p], bb1[p])));
            }
            acc[ct][0] = __builtin_amdgcn_mfma_f32_16x16x32_bf16(A0, B, acc[ct][0], 0, 0, 0);
            acc[ct][1] = __builtin_amdgcn_mfma_f32_16x16x32_bf16(A1, B, acc[ct][1], 0, 0, 0);
        }
    }

    // ---- epilogue: add b_b2, store. C/D: col(lane&15)=e_local, row(g*4+r)=i_local
    #pragma unroll
    for (int it = 0; it < 2; ++it) {
        f32x4 b2v = *(const f32x4*)&cb2[it * 16 + g * 4];
        #pragma unroll
        for (int ct = 0; ct < 4; ++ct) {
            int edge = e0 + ct * 16 + lrow;
            f32x4 vo = acc[ct][it] + b2v;
            *(f32x4*)&out[edge * 32 + it * 16 + g * 4] = vo;
        }
    }
}

extern "C" void kernel_launch(void* const* d_in, const int* in_sizes, int n_in,
                              void* d_out, int out_size, void* d_ws, size_t ws_size,
                              hipStream_t stream) {
    const float* h_i  = (const float*)d_in[0];
    const float* e_ij = (const float*)d_in[1];
    const float* W_A1 = (const float*)d_in[2];
    const float* b_A1 = (const float*)d_in[3];
    const float* W_A2 = (const float*)d_in[4];
    const float* b_A2 = (const float*)d_in[5];
    const float* W_b1 = (const float*)d_in[6];
    const float* b_b1 = (const float*)d_in[7];
    const float* W_b2 = (const float*)d_in[8];
    const float* b_b2 = (const float*)d_in[9];

    unsigned short* WT = (unsigned short*)d_ws;   // (131072 + 8192) * 2 = 278,528 B

    wt_build<<<(TAIL_OFF + TAIL_ELEM + 255) / 256, 256, 0, stream>>>(W_A2, b_A2, W_b2, WT);
    msg_main<<<E_TOT / 256, 256, 0, stream>>>(h_i, e_ij, W_A1, b_A1, W_b1, b_b1,
                                              b_b2, WT, (float*)d_out);
}

// Round 16
// 96.796 us; speedup vs baseline: 1.1763x; 1.0052x over previous
//
#include <hip/hip_runtime.h>

#define NH        32
#define HID       128
#define E_TOT     262144
#define CH_ELEM   8192      // chunk: 8 sl * 1024 elems = 16 KB
#define NCH_GRP   8         // chunks per wave-group (2 groups -> 16 main chunks = 128 s)
#define TAIL_OFF  131072    // 16 * 8192
#define TAIL_ELEM 8192      // tail chunk: 8 sl (sl 0..4 valid, 5..7 zero)

typedef float        f32x4 __attribute__((ext_vector_type(4)));
typedef short        s16x8 __attribute__((ext_vector_type(8)));
typedef unsigned int u32x4 __attribute__((ext_vector_type(4)));

static __device__ __forceinline__ short f2bf(float f) {
    __bf16 b = (__bf16)f;
    return __builtin_bit_cast(short, b);
}
static __device__ __forceinline__ float selu_f(float x) {
    const float kScale  = 1.0507009873554804934193349852946f;
    const float kAlphaS = 1.7580993408473768599402175208123f; // scale*alpha
    float neg = kAlphaS * (__expf(x) - 1.0f);
    return x > 0.0f ? kScale * x : neg;
}

// ---- pre-kernel: build WT in chunk-linear, LANE-LINEAR LDS order (R9 verbatim).
// main region gid < 131072: bits [c:4][sl:3][it:1][g:2][lrow:4][p:3]
//   kappa = c*256 + sl*32 + g*8 + p (0..4095) -> W_A2[kappa>>5][i*32 + (kappa&31)]
// tail region r = gid-131072: bits [sl:3][it:1][g:2][lrow:4][p:3]
//   kappa = 4096 + sl*32 + g*8 + p:
//     4096..4127 -> b_A2[i*32 + (kappa-4096)]
//     4128..4255 -> W_b2[kappa-4128][i]
//     else 0
// i = it*16 + lrow in both regions.
__global__ void wt_build(const float* __restrict__ W_A2, const float* __restrict__ b_A2,
                         const float* __restrict__ W_b2, unsigned short* __restrict__ WT) {
    int gid = blockIdx.x * 256 + threadIdx.x;
    if (gid >= TAIL_OFF + TAIL_ELEM) return;
    int it, g, lrow, p, kap;
    if (gid < TAIL_OFF) {
        int c  = gid >> 13;
        int r  = gid & 8191;
        int sl = r >> 10;
        it   = (r >> 9) & 1;
        g    = (r >> 7) & 3;
        lrow = (r >> 3) & 15;
        p    = r & 7;
        kap  = c * 256 + sl * 32 + g * 8 + p;
    } else {
        int r  = gid - TAIL_OFF;
        int sl = r >> 10;
        it   = (r >> 9) & 1;
        g    = (r >> 7) & 3;
        lrow = (r >> 3) & 15;
        p    = r & 7;
        kap  = 4096 + sl * 32 + g * 8 + p;
    }
    int i = it * 16 + lrow;
    float v = 0.0f;
    if (kap < 4096)      v = W_A2[(kap >> 5) * 1024 + i * 32 + (kap & 31)];
    else if (kap < 4128) v = b_A2[i * 32 + (kap - 4096)];
    else if (kap < 4256) v = W_b2[(kap - 4128) * 32 + i];
    WT[gid] = (unsigned short)f2bf(v);
}

typedef const __attribute__((address_space(1))) unsigned int GU32;
typedef __attribute__((address_space(3))) unsigned int LU32;
static __device__ __forceinline__ void gload_lds16(const void* g, void* l) {
    __builtin_amdgcn_global_load_lds((GU32*)g, (LU32*)l, 16, 0, 0);
}

// Split-K: 512 threads = 8 waves = 2 groups of 4 waves.
//   group grp (=wid>>2) accumulates chunks grp*8 .. grp*8+7 into its own acc,
//   using its own LDS buffer ldsW[grp]; group 1 also does the tail chunk.
//   Then group 1 spills acc to LDS and group 0 adds + stores.
// Within a group: wave wl (=wid&3) owns edges e0 = blk*256 + wl*64 (64 edges).
// NOTE: __launch_bounds__(512,4) — R9's (512,8) clamped VGPR to 32 and spilled
// everything (776 us). Cap 128 lets the compiler land at its natural ~60 VGPR,
// and 60 <= 64 allows 8 waves/SIMD -> 32 waves/CU (2x R15 residency).
__global__ void __launch_bounds__(512, 4)
msg_main(const float* __restrict__ h_i, const float* __restrict__ e_ij,
         const float* __restrict__ W_A1, const float* __restrict__ b_A1,
         const float* __restrict__ W_b1, const float* __restrict__ b_b1,
         const float* __restrict__ b_b2,
         const unsigned short* __restrict__ WT,
         float* __restrict__ out)
{
    __shared__ unsigned short ldsW[2][CH_ELEM];   // 2 x 16 KB, one per group
    __shared__ float cA1[HID], cBA1[HID], cB1a[HID], cB1b[HID], cb2[NH];

    const int tid  = threadIdx.x;
    const int lane = tid & 63;
    const int wid  = tid >> 6;
    const int grp  = wid >> 2;
    const int wl   = wid & 3;
    const int gtid = tid & 255;
    const int lrow = lane & 15;
    const int g    = lane >> 4;
    const int e0   = blockIdx.x * 256 + wl * 64;

    if (tid < HID) {
        cA1[tid]  = W_A1[tid];
        cBA1[tid] = b_A1[tid];
        cB1a[tid] = W_b1[tid];
        cB1b[tid] = b_b1[tid];
    }
    if (tid < NH) cb2[tid] = b_b2[tid];

    // lane owns edge e0+lane (within its wave)
    const float ev_own = e_ij[e0 + lane];

    // persistent bf16 h fragments (B operand)
    s16x8 hb[4];
    #pragma unroll
    for (int ct = 0; ct < 4; ++ct) {
        int er = e0 + ct * 16 + lrow;
        const float* hp = h_i + er * 32 + g * 8;
        f32x4 h0 = *(const f32x4*)hp;
        f32x4 h1 = *(const f32x4*)(hp + 4);
        #pragma unroll
        for (int p = 0; p < 4; ++p) {
            hb[ct][p]     = f2bf(h0[p]);
            hb[ct][p + 4] = f2bf(h1[p]);
        }
    }

    // per-col-tile edge scalar (for tail B construction, group 1 only uses it)
    float ev_ct[4];
    #pragma unroll
    for (int ct = 0; ct < 4; ++ct) ev_ct[ct] = __shfl(ev_own, ct * 16 + lrow);

    f32x4 acc[4][2];
    #pragma unroll
    for (int ct = 0; ct < 4; ++ct)
        #pragma unroll
        for (int it = 0; it < 2; ++it)
            acc[ct][it] = (f32x4){0.f, 0.f, 0.f, 0.f};
    const f32x4 zf = (f32x4){0.f, 0.f, 0.f, 0.f};

    float u_own[8];

    __syncthreads();        // consts visible

    for (int c = 0; c < NCH_GRP; ++c) {
        const int ch = grp * NCH_GRP + c;
        // stage this group's chunk (16 KB): 4 x 16B per group-thread
        #pragma unroll
        for (int r = 0; r < 4; ++r) {
            int eo = r * 2048 + gtid * 8;
            gload_lds16(WT + ch * CH_ELEM + eo, &ldsW[grp][eo]);
        }
        // u for the 8 s-steps of this chunk
        #pragma unroll
        for (int sl = 0; sl < 8; ++sl) {
            int s = ch * 8 + sl;
            u_own[sl] = selu_f(fmaf(ev_own, cA1[s], cBA1[s]));
        }
        __syncthreads();    // staging arrived (barrier drains vmcnt)

        #pragma unroll
        for (int sl = 0; sl < 8; ++sl) {
            u32x4 r0 = *(const u32x4*)&ldsW[grp][sl * 1024 +       lane * 8];
            u32x4 r1 = *(const u32x4*)&ldsW[grp][sl * 1024 + 512 + lane * 8];
            s16x8 A0 = __builtin_bit_cast(s16x8, r0);
            s16x8 A1 = __builtin_bit_cast(s16x8, r1);
            f32x4 u4[4];
            #pragma unroll
            for (int ct = 0; ct < 4; ++ct) {
                float uv = __shfl(u_own[sl], ct * 16 + lrow);
                u4[ct] = (f32x4){uv, uv, uv, uv};
            }
            {
                f32x4 t[4];
                #pragma unroll
                for (int ct = 0; ct < 4; ++ct)
                    t[ct] = __builtin_amdgcn_mfma_f32_16x16x32_bf16(A0, hb[ct], zf, 0, 0, 0);
                #pragma unroll
                for (int ct = 0; ct < 4; ++ct)
                    acc[ct][0] = __builtin_elementwise_fma(t[ct], u4[ct], acc[ct][0]);
            }
            {
                f32x4 t[4];
                #pragma unroll
                for (int ct = 0; ct < 4; ++ct)
                    t[ct] = __builtin_amdgcn_mfma_f32_16x16x32_bf16(A1, hb[ct], zf, 0, 0, 0);
                #pragma unroll
                for (int ct = 0; ct < 4; ++ct)
                    acc[ct][1] = __builtin_elementwise_fma(t[ct], u4[ct], acc[ct][1]);
            }
        }
        __syncthreads();    // all reads done before next chunk overwrites
    }

    // ---- tail chunk (group 1 only): stage sl 0..5 (need 0..4 = 5120; 3 rounds = 6144)
    if (grp == 1) {
        #pragma unroll
        for (int r = 0; r < 3; ++r) {
            int eo = r * 2048 + gtid * 8;
            gload_lds16(WT + TAIL_OFF + eo, &ldsW[1][eo]);
        }
    }
    __syncthreads();

    if (grp == 1) {
        // sl 0: b_A2 (pseudo-u = 1, B = h)
        {
            u32x4 r0 = *(const u32x4*)&ldsW[1][      lane * 8];
            u32x4 r1 = *(const u32x4*)&ldsW[1][512 + lane * 8];
            s16x8 A0 = __builtin_bit_cast(s16x8, r0);
            s16x8 A1 = __builtin_bit_cast(s16x8, r1);
            #pragma unroll
            for (int ct = 0; ct < 4; ++ct) {
                acc[ct][0] = __builtin_amdgcn_mfma_f32_16x16x32_bf16(A0, hb[ct], acc[ct][0], 0, 0, 0);
                acc[ct][1] = __builtin_amdgcn_mfma_f32_16x16x32_bf16(A1, hb[ct], acc[ct][1], 0, 0, 0);
            }
        }
        // sl 1..4: b-path (A = W_b2 cols, B = selu(e*W_b1 + b_b1))
        #pragma unroll
        for (int q = 0; q < 4; ++q) {
            u32x4 r0 = *(const u32x4*)&ldsW[1][(q + 1) * 1024 +       lane * 8];
            u32x4 r1 = *(const u32x4*)&ldsW[1][(q + 1) * 1024 + 512 + lane * 8];
            s16x8 A0 = __builtin_bit_cast(s16x8, r0);
            s16x8 A1 = __builtin_bit_cast(s16x8, r1);
            int tb = q * 32 + g * 8;
            f32x4 wb0 = *(const f32x4*)&cB1a[tb];
            f32x4 wb1 = *(const f32x4*)&cB1a[tb + 4];
            f32x4 bb0 = *(const f32x4*)&cB1b[tb];
            f32x4 bb1 = *(const f32x4*)&cB1b[tb + 4];
            #pragma unroll
            for (int ct = 0; ct < 4; ++ct) {
                s16x8 B;
                #pragma unroll
                for (int p = 0; p < 4; ++p) {
                    B[p]     = f2bf(selu_f(fmaf(ev_ct[ct], wb0[p], bb0[p])));
                    B[p + 4] = f2bf(selu_f(fmaf(ev_ct[ct], wb1[p], bb1[p])));
                }
                acc[ct][0] = __builtin_amdgcn_mfma_f32_16x16x32_bf16(A0, B, acc[ct][0], 0, 0, 0);
                acc[ct][1] = __builtin_amdgcn_mfma_f32_16x16x32_bf16(A1, B, acc[ct][1], 0, 0, 0);
            }
        }
    }
    __syncthreads();   // group-1 tail reads of ldsW done before red overlay writes

    // ---- split-K reduction: group 1 spills acc to LDS (conflict-free b32 interleave)
    float* red = (float*)&ldsW[0][0];   // 8192 f32 = 32 KB, overlays both buffers
    if (grp == 1) {
        #pragma unroll
        for (int ct = 0; ct < 4; ++ct)
            #pragma unroll
            for (int it = 0; it < 2; ++it)
                #pragma unroll
                for (int r = 0; r < 4; ++r)
                    red[(ct * 8 + it * 4 + r) * 256 + gtid] = acc[ct][it][r];
    }
    __syncthreads();

    // ---- epilogue (group 0): add partner partial + b_b2, store
    if (grp == 0) {
        #pragma unroll
        for (int it = 0; it < 2; ++it) {
            f32x4 b2v = *(const f32x4*)&cb2[it * 16 + g * 4];
            #pragma unroll
            for (int ct = 0; ct < 4; ++ct) {
                f32x4 po;
                #pragma unroll
                for (int r = 0; r < 4; ++r)
                    po[r] = red[(ct * 8 + it * 4 + r) * 256 + gtid];
                int edge = e0 + ct * 16 + lrow;
                f32x4 vo = acc[ct][it] + po + b2v;
                *(f32x4*)&out[edge * 32 + it * 16 + g * 4] = vo;
            }
        }
    }
}

extern "C" void kernel_launch(void* const* d_in, const int* in_sizes, int n_in,
                              void* d_out, int out_size, void* d_ws, size_t ws_size,
                              hipStream_t stream) {
    const float* h_i  = (const float*)d_in[0];
    const float* e_ij = (const float*)d_in[1];
    const float* W_A1 = (const float*)d_in[2];
    const float* b_A1 = (const float*)d_in[3];
    const float* W_A2 = (const float*)d_in[4];
    const float* b_A2 = (const float*)d_in[5];
    const float* W_b1 = (const float*)d_in[6];
    const float* b_b1 = (const float*)d_in[7];
    const float* W_b2 = (const float*)d_in[8];
    const float* b_b2 = (const float*)d_in[9];

    unsigned short* WT = (unsigned short*)d_ws;   // (131072 + 8192) * 2 = 278,528 B

    wt_build<<<(TAIL_OFF + TAIL_ELEM + 255) / 256, 256, 0, stream>>>(W_A2, b_A2, W_b2, WT);
    msg_main<<<E_TOT / 256, 512, 0, stream>>>(h_i, e_ij, W_A1, b_A1, W_b1, b_b1,
                                              b_b2, WT, (float*)d_out);
}